// Round 1
// baseline (94.017 us; speedup 1.0000x reference)
//
#include <hip/hip_runtime.h>
#include <hip/hip_bf16.h>

typedef __attribute__((ext_vector_type(8))) short s16x8;
typedef __attribute__((ext_vector_type(4))) float f32x4;

#define WAVES 8
#define TROWS 16            // rows per wave
#define ROWS_PER_BLOCK (WAVES * TROWS)   // 128

__device__ __forceinline__ short f2bf(float f) {
    unsigned int u = __float_as_uint(f);
    u += 0x7fffu + ((u >> 16) & 1u);     // round-to-nearest-even
    return (short)(u >> 16);
}

// swizzled ushort index for a [rows][128] bf16 tile; col must be mult of 8 for 16B ops
__device__ __forceinline__ int swz(int row, int col) {
    return (row * 128 + col) ^ ((row & 7) << 3);
}

__device__ __forceinline__ void store8(short* tile, int row, int col, float4 a, float4 b) {
    s16x8 v;
    v[0] = f2bf(a.x); v[1] = f2bf(a.y); v[2] = f2bf(a.z); v[3] = f2bf(a.w);
    v[4] = f2bf(b.x); v[5] = f2bf(b.y); v[6] = f2bf(b.z); v[7] = f2bf(b.w);
    *(s16x8*)(tile + swz(row, col)) = v;
}

__launch_bounds__(512, 2)
__global__ void edgeface_kernel(
    const float* __restrict__ topo, const int* __restrict__ esid,
    const float* __restrict__ W1, const float* __restrict__ b1,
    const float* __restrict__ W2, const float* __restrict__ b2,
    const float* __restrict__ W3, const float* __restrict__ b3,
    float* __restrict__ out, int nRows, int kg)
{
    __shared__ __align__(16) short sW1[128 * 128];   // Wt[n][k] swizzled, bf16
    __shared__ __align__(16) short sW2[128 * 128];
    __shared__ __align__(16) short sW3[16 * 128];    // rows 0..1 = W3^T, rest 0
    __shared__ float sB1[128], sB2[128];
    __shared__ __align__(16) short sX[WAVES * TROWS * 128]; // per-wave private tiles

    const int tid = threadIdx.x;

    // ---- stage weights (once per persistent block) ----
    for (int idx = tid; idx < 128 * 128; idx += 512) {
        int kk = idx >> 7, n = idx & 127;        // consecutive tid -> consecutive n (coalesced)
        int d = swz(n, kk);
        sW1[d] = f2bf(W1[idx]);                  // W[k][n] -> Wt[n][k]
        sW2[d] = f2bf(W2[idx]);
    }
    for (int idx = tid; idx < 16 * 128; idx += 512) {
        int n = idx >> 7, kk = idx & 127;
        sW3[swz(n, kk)] = (n < 2) ? f2bf(W3[kk * 2 + n]) : (short)0;
    }
    if (tid < 128) { sB1[tid] = b1[tid]; sB2[tid] = b2[tid]; }
    __syncthreads();

    const int w    = tid >> 6;
    const int lane = tid & 63;
    short* tile = sX + w * (TROWS * 128);

    const int r = lane & 15;   // A-row / D-col within 16
    const int g = lane >> 4;   // k-quarter / D-row-group

    const int nTiles = (nRows + ROWS_PER_BLOCK - 1) / ROWS_PER_BLOCK;

    for (int tI = blockIdx.x; tI < nTiles; tI += gridDim.x) {
        const int rowBase = tI * ROWS_PER_BLOCK + w * TROWS;

        // ---- gather: 16 rows, 4 lanes/row, 16 floats/lane per segment ----
        {
            int j = lane >> 2, q = lane & 3;
            int R  = rowBase + j;
            int Rc = min(R, nRows - 1);
            int n  = Rc / 3, f = Rc - n * 3;
            int i0 = esid[n * 3 + 0], i1 = esid[n * 3 + 1], i2 = esid[n * 3 + 2];
            long be = (((long)i0 * kg + i1) * kg + i2) * 64;
            int j0 = max(i0 - (f == 0 ? 1 : 0), 0);
            int j1 = max(i1 - (f == 1 ? 1 : 0), 0);
            int j2 = max(i2 - (f == 2 ? 1 : 0), 0);
            long bn = (((long)j0 * kg + j1) * kg + j2) * 64;
            const float4* pe = (const float4*)(topo + be) + q * 4;
            const float4* pn = (const float4*)(topo + bn) + q * 4;
            float4 e0 = pe[0], e1 = pe[1], e2 = pe[2], e3 = pe[3];
            float4 v0 = pn[0], v1 = pn[1], v2 = pn[2], v3 = pn[3];
            // WAR fence: previous iteration's layer-3 reads of `tile` must land first
            asm volatile("s_waitcnt lgkmcnt(0)" ::: "memory");
            store8(tile, j, q * 16 + 0, e0, e1);
            store8(tile, j, q * 16 + 8, e2, e3);
            store8(tile, j, 64 + q * 16 + 0, v0, v1);
            store8(tile, j, 64 + q * 16 + 8, v2, v3);
        }
        asm volatile("s_waitcnt lgkmcnt(0)" ::: "memory");

        f32x4 acc[8];
        s16x8 a[4];

        // ---- layer 1: H1 = relu(X @ W1 + b1) ----
        #pragma unroll
        for (int ks = 0; ks < 4; ++ks)
            a[ks] = *(const s16x8*)(tile + swz(r, ks * 32 + g * 8));
        #pragma unroll
        for (int t = 0; t < 8; ++t) {
            f32x4 c = {0.f, 0.f, 0.f, 0.f};
            #pragma unroll
            for (int ks = 0; ks < 4; ++ks) {
                s16x8 bf = *(const s16x8*)(sW1 + swz(t * 16 + r, ks * 32 + g * 8));
                c = __builtin_amdgcn_mfma_f32_16x16x32_bf16(a[ks], bf, c, 0, 0, 0);
            }
            acc[t] = c;
        }
        asm volatile("s_waitcnt lgkmcnt(0)" ::: "memory");
        #pragma unroll
        for (int t = 0; t < 8; ++t) {
            #pragma unroll
            for (int i = 0; i < 4; ++i) {
                int row = g * 4 + i, col = t * 16 + r;
                float v = fmaxf(acc[t][i] + sB1[col], 0.f);
                tile[swz(row, col)] = f2bf(v);
            }
        }
        asm volatile("s_waitcnt lgkmcnt(0)" ::: "memory");

        // ---- layer 2: H2 = relu(H1 @ W2 + b2) ----
        #pragma unroll
        for (int ks = 0; ks < 4; ++ks)
            a[ks] = *(const s16x8*)(tile + swz(r, ks * 32 + g * 8));
        #pragma unroll
        for (int t = 0; t < 8; ++t) {
            f32x4 c = {0.f, 0.f, 0.f, 0.f};
            #pragma unroll
            for (int ks = 0; ks < 4; ++ks) {
                s16x8 bf = *(const s16x8*)(sW2 + swz(t * 16 + r, ks * 32 + g * 8));
                c = __builtin_amdgcn_mfma_f32_16x16x32_bf16(a[ks], bf, c, 0, 0, 0);
            }
            acc[t] = c;
        }
        asm volatile("s_waitcnt lgkmcnt(0)" ::: "memory");
        #pragma unroll
        for (int t = 0; t < 8; ++t) {
            #pragma unroll
            for (int i = 0; i < 4; ++i) {
                int row = g * 4 + i, col = t * 16 + r;
                float v = fmaxf(acc[t][i] + sB2[col], 0.f);
                tile[swz(row, col)] = f2bf(v);
            }
        }
        asm volatile("s_waitcnt lgkmcnt(0)" ::: "memory");

        // ---- layer 3: logits = H2 @ W3 + b3 (padded to 16 cols) ----
        #pragma unroll
        for (int ks = 0; ks < 4; ++ks)
            a[ks] = *(const s16x8*)(tile + swz(r, ks * 32 + g * 8));
        f32x4 c3 = {0.f, 0.f, 0.f, 0.f};
        #pragma unroll
        for (int ks = 0; ks < 4; ++ks) {
            s16x8 bf = *(const s16x8*)(sW3 + swz(r, ks * 32 + g * 8));
            c3 = __builtin_amdgcn_mfma_f32_16x16x32_bf16(a[ks], bf, c3, 0, 0, 0);
        }
        float bown = (r < 2) ? b3[r] : 0.f;
        #pragma unroll
        for (int i = 0; i < 4; ++i) {
            int row = g * 4 + i;
            float o  = c3[i] + bown;
            float oo = __shfl_xor(o, 1, 64);        // partner logit (cols 0<->1)
            float p  = 1.f / (1.f + __expf(oo - o));
            int R = rowBase + row;
            if (R < nRows && r < 2) {
                int n = R / 3, f = R - n * 3;
                out[n * 6 + r * 3 + f] = p;          // (N, 2, 3) layout
            }
        }
    }
}

extern "C" void kernel_launch(void* const* d_in, const int* in_sizes, int n_in,
                              void* d_out, int out_size, void* d_ws, size_t ws_size,
                              hipStream_t stream) {
    const float* topo = (const float*)d_in[0];
    const int*   esid = (const int*)d_in[1];
    const float* W1 = (const float*)d_in[2];
    const float* b1 = (const float*)d_in[3];
    const float* W2 = (const float*)d_in[4];
    const float* b2 = (const float*)d_in[5];
    const float* W3 = (const float*)d_in[6];
    const float* b3 = (const float*)d_in[7];
    float* out = (float*)d_out;

    int nRows = in_sizes[1];              // N_es * 3 rows (esid flat count)
    // recover F from W1/b1 sizes, then k from topo volume
    int H = in_sizes[3];
    int F = (in_sizes[2] / H) / 2;
    long vol = (long)in_sizes[0] / F;
    int kg = 1;
    while ((long)(kg + 1) * (kg + 1) * (kg + 1) <= vol) ++kg;

    if (nRows <= 0) return;
    edgeface_kernel<<<dim3(256), dim3(512), 0, stream>>>(
        topo, esid, W1, b1, W2, b2, W3, b3, out, nRows, kg);
}